// Round 2
// baseline (356.803 us; speedup 1.0000x reference)
//
#include <hip/hip_runtime.h>
#include <hip/hip_bf16.h>
#include <math.h>

#define N_NODES 30000
#define MAXN 32
#define DIM 128
#define NHEAD 4
#define HDIM 32
#define ROWS 16
#define LN_EPS 1e-5f

typedef __hip_bfloat16 bf16;

// ---------------- Kernel 1: QKV projection ----------------
// Q -> d_out (f32, consumed as residual + attention query by kernel 2)
// K,V -> ws as bf16 (halves gather traffic)
__global__ __launch_bounds__(128) void qkv_kernel(
    const float* __restrict__ h,
    const float* __restrict__ Wq,
    const float* __restrict__ Wk,
    const float* __restrict__ Wv,
    float* __restrict__ Qout,
    bf16* __restrict__ Kout,
    bf16* __restrict__ Vout)
{
    __shared__ float hs[ROWS][DIM];
    const int t = threadIdx.x;          // output column d = t
    const int r0 = blockIdx.x * ROWS;

    for (int r = 0; r < ROWS; ++r)
        hs[r][t] = h[(size_t)(r0 + r) * DIM + t];
    __syncthreads();

    float aq[ROWS], ak[ROWS], av[ROWS];
#pragma unroll
    for (int r = 0; r < ROWS; ++r) { aq[r] = 0.f; ak[r] = 0.f; av[r] = 0.f; }

#pragma unroll 4
    for (int k = 0; k < DIM; ++k) {
        float wq = Wq[k * DIM + t];
        float wk = Wk[k * DIM + t];
        float wv = Wv[k * DIM + t];
#pragma unroll
        for (int r = 0; r < ROWS; ++r) {
            float hv = hs[r][k];
            aq[r] = fmaf(hv, wq, aq[r]);
            ak[r] = fmaf(hv, wk, ak[r]);
            av[r] = fmaf(hv, wv, av[r]);
        }
    }

    for (int r = 0; r < ROWS; ++r) {
        int row = r0 + r;
        Qout[(size_t)row * DIM + t] = aq[r];
        Kout[(size_t)row * DIM + t] = __float2bfloat16(ak[r]);
        Vout[(size_t)row * DIM + t] = __float2bfloat16(av[r]);
    }
}

__device__ inline void unpack8(uint4 p, float* dst) {
    uint w[4] = { p.x, p.y, p.z, p.w };
#pragma unroll
    for (int i = 0; i < 4; ++i) {
        dst[2 * i]     = __uint_as_float((w[i] & 0xffffu) << 16);
        dst[2 * i + 1] = __uint_as_float(w[i] & 0xffff0000u);
    }
}

// ---------------- Kernel 2: gather-attention + FC + GELU + LN ----------------
// One 128-thread block per node.
__global__ __launch_bounds__(128) void attn_kernel(
    const float* __restrict__ Qbuf,       // d_out currently holds Q
    const bf16* __restrict__ Kbuf,
    const bf16* __restrict__ Vbuf,
    const int* __restrict__ nidx,         // int32 per harness contract
    const int* __restrict__ nmask,
    const float* __restrict__ Wfc,
    const float* __restrict__ bfc,
    const float* __restrict__ gamma,
    const float* __restrict__ beta,
    float* __restrict__ out)
{
    __shared__ float Ks[MAXN][DIM + 4];
    __shared__ float Vs[MAXN][DIM + 4];
    __shared__ float qs[DIM];
    __shared__ float sc[MAXN][NHEAD + 1];
    __shared__ float al[MAXN][NHEAD + 1];
    __shared__ float rowv[DIM];
    __shared__ float red[2][2];
    __shared__ int idx_s[MAXN];

    const int n = blockIdx.x;
    const int t = threadIdx.x;

    qs[t] = Qbuf[(size_t)n * DIM + t];
    if (t < MAXN) idx_s[t] = nidx[(size_t)n * MAXN + t];
    __syncthreads();

    // ---- gather K,V rows (bf16, 256B each) into LDS as f32 ----
    {
        const int rg = t >> 4;   // 0..7  (row within group of 8)
        const int e  = t & 15;   // 0..15 (16B chunk within row)
        for (int it = 0; it < 4; ++it) {
            int m = it * 8 + rg;
            int src = idx_s[m];
            const uint4* kp = (const uint4*)((const ushort*)(Kbuf + (size_t)src * DIM) + e * 8);
            const uint4* vp = (const uint4*)((const ushort*)(Vbuf + (size_t)src * DIM) + e * 8);
            uint4 kd = *kp;
            uint4 vd = *vp;
            unpack8(kd, &Ks[m][e * 8]);
            unpack8(vd, &Vs[m][e * 8]);
        }
    }
    __syncthreads();

    // ---- scores: thread t = (m, head) ----
    {
        const int m = t >> 2;
        const int hh = t & 3;
        const float* qp = qs + hh * HDIM;
        const float* kp = &Ks[m][hh * HDIM];
        float acc = 0.f;
#pragma unroll
        for (int d = 0; d < HDIM; ++d) acc = fmaf(qp[d], kp[d], acc);
        acc *= 0.17677669529663687f;   // 1/sqrt(32)
        if (nmask[(size_t)n * MAXN + m] == 0) acc = -1e9f;
        sc[m][hh] = acc;
    }
    __syncthreads();

    // ---- softmax over m, per head (4 threads, serial over 32) ----
    if (t < NHEAD) {
        const int hh = t;
        float mx = -INFINITY;
        for (int m = 0; m < MAXN; ++m) mx = fmaxf(mx, sc[m][hh]);
        float s = 0.f;
        for (int m = 0; m < MAXN; ++m) {
            float ev = expf(sc[m][hh] - mx);
            al[m][hh] = ev;
            s += ev;
        }
        float inv = 1.0f / s;
        for (int m = 0; m < MAXN; ++m) al[m][hh] *= inv;
    }
    __syncthreads();

    // ---- weighted V sum: thread t = output dim d ----
    {
        const int hh = t >> 5;   // head of dim t
        float o = 0.f;
#pragma unroll
        for (int m = 0; m < MAXN; ++m) o = fmaf(al[m][hh], Vs[m][t], o);
        rowv[t] = o;
    }
    __syncthreads();

    // ---- FC + bias + residual(Q) + exact GELU ----
    float x = bfc[t] + qs[t];
#pragma unroll 4
    for (int k = 0; k < DIM; ++k)
        x = fmaf(rowv[k], Wfc[k * DIM + t], x);

    float g = 0.5f * x * (1.0f + erff(x * 0.70710678118654752f));

    // ---- LayerNorm over 128 dims (one value per thread) ----
    float s1 = g, s2 = g * g;
#pragma unroll
    for (int off = 1; off < 64; off <<= 1) {
        s1 += __shfl_xor(s1, off);
        s2 += __shfl_xor(s2, off);
    }
    const int wid = t >> 6;
    if ((t & 63) == 0) { red[wid][0] = s1; red[wid][1] = s2; }
    __syncthreads();
    float ts1 = red[0][0] + red[1][0];
    float ts2 = red[0][1] + red[1][1];
    float mean = ts1 * (1.0f / DIM);
    float var  = ts2 * (1.0f / DIM) - mean * mean;
    float invs = rsqrtf(var + LN_EPS);
    out[(size_t)n * DIM + t] = (g - mean) * invs * gamma[t] + beta[t];
}

extern "C" void kernel_launch(void* const* d_in, const int* in_sizes, int n_in,
                              void* d_out, int out_size, void* d_ws, size_t ws_size,
                              hipStream_t stream) {
    (void)in_sizes; (void)n_in; (void)out_size; (void)ws_size;
    const float* h     = (const float*)d_in[0];
    const float* Wq    = (const float*)d_in[1];
    const float* Wk    = (const float*)d_in[2];
    const float* Wv    = (const float*)d_in[3];
    const float* Wfc   = (const float*)d_in[4];
    const float* bfc   = (const float*)d_in[5];
    const float* gamma = (const float*)d_in[6];
    const float* beta  = (const float*)d_in[7];
    const int* nidx    = (const int*)d_in[8];   // int32 per harness contract
    const int* nmask   = (const int*)d_in[9];

    bf16* Kbuf = (bf16*)d_ws;
    bf16* Vbuf = Kbuf + (size_t)N_NODES * DIM;
    float* Q   = (float*)d_out;

    qkv_kernel<<<N_NODES / ROWS, 128, 0, stream>>>(h, Wq, Wk, Wv, Q, Kbuf, Vbuf);
    attn_kernel<<<N_NODES, 128, 0, stream>>>(Q, Kbuf, Vbuf, nidx, nmask,
                                             Wfc, bfc, gamma, beta, (float*)d_out);
}

// Round 3
// 169.850 us; speedup vs baseline: 2.1007x; 2.1007x over previous
//
#include <hip/hip_runtime.h>
#include <hip/hip_bf16.h>
#include <math.h>

#define N_NODES 30000
#define MAXN 32
#define DIM 128
#define NHEAD 4
#define HDIM 32
#define ROWS 16
#define NPB 4            // nodes per block in attn kernel
#define LN_EPS 1e-5f

typedef __hip_bfloat16 bf16;

// ---------------- Kernel 1: QKV projection ----------------
// Q -> d_out (f32, consumed as residual + attention query by kernel 2)
// K,V -> ws as bf16 (halves gather traffic)
__global__ __launch_bounds__(128) void qkv_kernel(
    const float* __restrict__ h,
    const float* __restrict__ Wq,
    const float* __restrict__ Wk,
    const float* __restrict__ Wv,
    float* __restrict__ Qout,
    bf16* __restrict__ Kout,
    bf16* __restrict__ Vout)
{
    __shared__ float hs[ROWS][DIM];
    const int t = threadIdx.x;          // output column d = t
    const int r0 = blockIdx.x * ROWS;

    for (int r = 0; r < ROWS; ++r)
        hs[r][t] = h[(size_t)(r0 + r) * DIM + t];
    __syncthreads();

    float aq[ROWS], ak[ROWS], av[ROWS];
#pragma unroll
    for (int r = 0; r < ROWS; ++r) { aq[r] = 0.f; ak[r] = 0.f; av[r] = 0.f; }

#pragma unroll 4
    for (int k = 0; k < DIM; ++k) {
        float wq = Wq[k * DIM + t];
        float wk = Wk[k * DIM + t];
        float wv = Wv[k * DIM + t];
#pragma unroll
        for (int r = 0; r < ROWS; ++r) {
            float hv = hs[r][k];
            aq[r] = fmaf(hv, wq, aq[r]);
            ak[r] = fmaf(hv, wk, ak[r]);
            av[r] = fmaf(hv, wv, av[r]);
        }
    }

    for (int r = 0; r < ROWS; ++r) {
        int row = r0 + r;
        Qout[(size_t)row * DIM + t] = aq[r];
        Kout[(size_t)row * DIM + t] = __float2bfloat16(ak[r]);
        Vout[(size_t)row * DIM + t] = __float2bfloat16(av[r]);
    }
}

__device__ inline float bf16_hi(uint w) { return __uint_as_float(w & 0xffff0000u); }
__device__ inline float bf16_lo(uint w) { return __uint_as_float((w & 0xffffu) << 16); }

// ---------------- Kernel 2: gather-attention + FC + GELU + LN ----------------
// NPB nodes per 512-thread block; each 128-thread sub-group owns one node.
// No K/V LDS staging: every K/V element is used exactly once, so we read
// straight from global (L2/L3-resident bf16) in the compute-natural layout.
__global__ __launch_bounds__(512, 8) void attn_kernel(
    const float* __restrict__ Qbuf,       // d_out currently holds Q
    const bf16* __restrict__ Kbuf,
    const bf16* __restrict__ Vbuf,
    const int* __restrict__ nidx,         // int32 per harness contract
    const int* __restrict__ nmask,
    const float* __restrict__ Wfc,
    const float* __restrict__ bfc,
    const float* __restrict__ gamma,
    const float* __restrict__ beta,
    float* __restrict__ out)
{
    __shared__ float qs[NPB][DIM];
    __shared__ float al[NPB][NHEAD][MAXN];
    __shared__ float rowv[NPB][DIM];
    __shared__ int   idx_s[NPB][MAXN];
    __shared__ float red[NPB][2][2];

    const int t  = threadIdx.x;
    const int nn = t >> 7;        // node slot within block
    const int tl = t & 127;       // thread within node
    const int n  = blockIdx.x * NPB + nn;

    const float qreg = Qbuf[(size_t)n * DIM + tl];
    qs[nn][tl] = qreg;
    if (tl < MAXN) idx_s[nn][tl] = nidx[(size_t)n * MAXN + tl];
    __syncthreads();

    // ---- scores + softmax: tl = h*32 + m ----
    {
        const int hh = tl >> 5;
        const int m  = tl & 31;
        const uint4* kp = (const uint4*)((const ushort*)Kbuf
                          + (size_t)idx_s[nn][m] * DIM + hh * HDIM);
        const float* qp = &qs[nn][hh * HDIM];
        float acc = 0.f;
#pragma unroll
        for (int c = 0; c < 4; ++c) {           // 4 x 16B = 64B = 32 bf16
            uint4 kd = kp[c];
            uint w[4] = { kd.x, kd.y, kd.z, kd.w };
#pragma unroll
            for (int i = 0; i < 4; ++i) {
                acc = fmaf(qp[c * 8 + 2 * i],     bf16_lo(w[i]), acc);
                acc = fmaf(qp[c * 8 + 2 * i + 1], bf16_hi(w[i]), acc);
            }
        }
        acc *= 0.17677669529663687f;            // 1/sqrt(32)
        if (nmask[(size_t)n * MAXN + m] == 0) acc = -1e9f;

        // softmax across the 32-lane group (xor offsets 1..16 stay in-group)
        float mx = acc;
#pragma unroll
        for (int off = 1; off < 32; off <<= 1)
            mx = fmaxf(mx, __shfl_xor(mx, off));
        float e = expf(acc - mx);
        float s = e;
#pragma unroll
        for (int off = 1; off < 32; off <<= 1)
            s += __shfl_xor(s, off);
        al[nn][hh][m] = e / s;
    }
    __syncthreads();

    // ---- weighted V sum: tl = output dim ----
    {
        const int hh = tl >> 5;
        const ushort* vb = (const ushort*)Vbuf;
        float o = 0.f;
#pragma unroll
        for (int m = 0; m < MAXN; ++m) {
            float v = __uint_as_float(((uint)vb[(size_t)idx_s[nn][m] * DIM + tl]) << 16);
            o = fmaf(al[nn][hh][m], v, o);
        }
        rowv[nn][tl] = o;
    }
    __syncthreads();

    // ---- FC + bias + residual(Q) + exact GELU ----
    float x0 = bfc[tl] + qreg, x1 = 0.f, x2 = 0.f, x3 = 0.f;
#pragma unroll 8
    for (int k = 0; k < DIM; k += 4) {
        x0 = fmaf(rowv[nn][k],     Wfc[(k)     * DIM + tl], x0);
        x1 = fmaf(rowv[nn][k + 1], Wfc[(k + 1) * DIM + tl], x1);
        x2 = fmaf(rowv[nn][k + 2], Wfc[(k + 2) * DIM + tl], x2);
        x3 = fmaf(rowv[nn][k + 3], Wfc[(k + 3) * DIM + tl], x3);
    }
    float x = (x0 + x1) + (x2 + x3);

    float g = 0.5f * x * (1.0f + erff(x * 0.70710678118654752f));

    // ---- LayerNorm over 128 dims (2 waves per node) ----
    float s1 = g, s2 = g * g;
#pragma unroll
    for (int off = 1; off < 64; off <<= 1) {
        s1 += __shfl_xor(s1, off);
        s2 += __shfl_xor(s2, off);
    }
    const int wid = (tl >> 6);
    if ((tl & 63) == 0) { red[nn][wid][0] = s1; red[nn][wid][1] = s2; }
    __syncthreads();
    float ts1 = red[nn][0][0] + red[nn][1][0];
    float ts2 = red[nn][0][1] + red[nn][1][1];
    float mean = ts1 * (1.0f / DIM);
    float var  = ts2 * (1.0f / DIM) - mean * mean;
    float invs = rsqrtf(var + LN_EPS);
    out[(size_t)n * DIM + tl] = (g - mean) * invs * gamma[tl] + beta[tl];
}

extern "C" void kernel_launch(void* const* d_in, const int* in_sizes, int n_in,
                              void* d_out, int out_size, void* d_ws, size_t ws_size,
                              hipStream_t stream) {
    (void)in_sizes; (void)n_in; (void)out_size; (void)ws_size;
    const float* h     = (const float*)d_in[0];
    const float* Wq    = (const float*)d_in[1];
    const float* Wk    = (const float*)d_in[2];
    const float* Wv    = (const float*)d_in[3];
    const float* Wfc   = (const float*)d_in[4];
    const float* bfc   = (const float*)d_in[5];
    const float* gamma = (const float*)d_in[6];
    const float* beta  = (const float*)d_in[7];
    const int* nidx    = (const int*)d_in[8];   // int32 per harness contract
    const int* nmask   = (const int*)d_in[9];

    bf16* Kbuf = (bf16*)d_ws;
    bf16* Vbuf = Kbuf + (size_t)N_NODES * DIM;
    float* Q   = (float*)d_out;

    qkv_kernel<<<N_NODES / ROWS, 128, 0, stream>>>(h, Wq, Wk, Wv, Q, Kbuf, Vbuf);
    attn_kernel<<<N_NODES / NPB, 512, 0, stream>>>(Q, Kbuf, Vbuf, nidx, nmask,
                                                   Wfc, bfc, gamma, beta, (float*)d_out);
}

// Round 4
// 136.569 us; speedup vs baseline: 2.6126x; 1.2437x over previous
//
#include <hip/hip_runtime.h>
#include <hip/hip_bf16.h>
#include <math.h>

#define N_NODES 30000
#define MAXN 32
#define DIM 128
#define NHEAD 4
#define HDIM 32
#define ROWS 16
#define NPB 4            // nodes per block in attn kernel
#define LN_EPS 1e-5f

typedef __hip_bfloat16 bf16;
typedef __attribute__((ext_vector_type(8))) short bf16x8;
typedef __attribute__((ext_vector_type(4))) float f32x4;

// ---------------- Kernel 1: QKV projection ----------------
__global__ __launch_bounds__(128) void qkv_kernel(
    const float* __restrict__ h,
    const float* __restrict__ Wq,
    const float* __restrict__ Wk,
    const float* __restrict__ Wv,
    float* __restrict__ Qout,
    bf16* __restrict__ Kout,
    bf16* __restrict__ Vout)
{
    __shared__ float hs[ROWS][DIM];
    const int t = threadIdx.x;
    const int r0 = blockIdx.x * ROWS;

    for (int r = 0; r < ROWS; ++r)
        hs[r][t] = h[(size_t)(r0 + r) * DIM + t];
    __syncthreads();

    float aq[ROWS], ak[ROWS], av[ROWS];
#pragma unroll
    for (int r = 0; r < ROWS; ++r) { aq[r] = 0.f; ak[r] = 0.f; av[r] = 0.f; }

#pragma unroll 4
    for (int k = 0; k < DIM; ++k) {
        float wq = Wq[k * DIM + t];
        float wk = Wk[k * DIM + t];
        float wv = Wv[k * DIM + t];
#pragma unroll
        for (int r = 0; r < ROWS; ++r) {
            float hv = hs[r][k];
            aq[r] = fmaf(hv, wq, aq[r]);
            ak[r] = fmaf(hv, wk, ak[r]);
            av[r] = fmaf(hv, wv, av[r]);
        }
    }

    for (int r = 0; r < ROWS; ++r) {
        int row = r0 + r;
        Qout[(size_t)row * DIM + t] = aq[r];
        Kout[(size_t)row * DIM + t] = __float2bfloat16(ak[r]);
        Vout[(size_t)row * DIM + t] = __float2bfloat16(av[r]);
    }
}

// ---------------- prep: Wfc -> WfcT bf16 [n][k] ----------------
__global__ __launch_bounds__(128) void prep_kernel(
    const float* __restrict__ Wfc, bf16* __restrict__ WfcT)
{
    const int n = blockIdx.x, k = threadIdx.x;
    WfcT[n * DIM + k] = __float2bfloat16(Wfc[k * DIM + n]);
}

__device__ inline float bf_hi(uint w) { return __uint_as_float(w & 0xffff0000u); }
__device__ inline float bf_lo(uint w) { return __uint_as_float((w & 0xffffu) << 16); }

// ---------------- Kernel 2: gather-attention only ----------------
// NPB nodes per 512-thread block; 128 threads per node. Writes rowv (bf16).
__global__ __launch_bounds__(512, 8) void attn_kernel(
    const float* __restrict__ Qbuf,
    const bf16* __restrict__ Kbuf,
    const bf16* __restrict__ Vbuf,
    const int* __restrict__ nidx,
    const int* __restrict__ nmask,
    bf16* __restrict__ rowv_out)
{
    __shared__ float qs[NPB][DIM];
    __shared__ float al[NPB][NHEAD][MAXN];
    __shared__ float pv1[NPB][64][2];
    __shared__ int   idx_s[NPB][MAXN];

    const int t  = threadIdx.x;
    const int nn = t >> 7;
    const int tl = t & 127;
    const int n  = blockIdx.x * NPB + nn;

    qs[nn][tl] = Qbuf[(size_t)n * DIM + tl];
    if (tl < MAXN) idx_s[nn][tl] = nidx[(size_t)n * MAXN + tl];
    __syncthreads();

    // ---- scores + softmax: tl = h*32 + m ----
    {
        const int hh = tl >> 5;
        const int m  = tl & 31;
        const uint4* kp = (const uint4*)((const ushort*)Kbuf
                          + (size_t)idx_s[nn][m] * DIM + hh * HDIM);
        const float4* qp4 = (const float4*)(&qs[nn][hh * HDIM]);
        float acc = 0.f;
#pragma unroll
        for (int c = 0; c < 4; ++c) {
            uint4 kd = kp[c];
            float4 q0 = qp4[2 * c], q1 = qp4[2 * c + 1];
            acc = fmaf(q0.x, bf_lo(kd.x), acc);
            acc = fmaf(q0.y, bf_hi(kd.x), acc);
            acc = fmaf(q0.z, bf_lo(kd.y), acc);
            acc = fmaf(q0.w, bf_hi(kd.y), acc);
            acc = fmaf(q1.x, bf_lo(kd.z), acc);
            acc = fmaf(q1.y, bf_hi(kd.z), acc);
            acc = fmaf(q1.z, bf_lo(kd.w), acc);
            acc = fmaf(q1.w, bf_hi(kd.w), acc);
        }
        acc *= 0.17677669529663687f;            // 1/sqrt(32)
        if (nmask[(size_t)n * MAXN + m] == 0) acc = -1e9f;

        float mx = acc;
#pragma unroll
        for (int off = 1; off < 32; off <<= 1)
            mx = fmaxf(mx, __shfl_xor(mx, off));
        float e = expf(acc - mx);
        float s = e;
#pragma unroll
        for (int off = 1; off < 32; off <<= 1)
            s += __shfl_xor(s, off);
        al[nn][hh][m] = e / s;
    }
    __syncthreads();

    // ---- weighted V sum: 2-way m-split, packed bf16x2 loads ----
    {
        const int part = tl >> 6;     // 0: m 0..15, 1: m 16..31
        const int d2   = tl & 63;     // dim pair (2*d2, 2*d2+1)
        const int hh2  = d2 >> 4;
        const uint* vb = (const uint*)Vbuf;
        float a0 = 0.f, a1 = 0.f;
#pragma unroll
        for (int mm = 0; mm < 16; ++mm) {
            int m = part * 16 + mm;
            uint v = vb[(size_t)idx_s[nn][m] * (DIM / 2) + d2];
            float alv = al[nn][hh2][m];
            a0 = fmaf(alv, bf_lo(v), a0);
            a1 = fmaf(alv, bf_hi(v), a1);
        }
        if (part == 1) { pv1[nn][d2][0] = a0; pv1[nn][d2][1] = a1; }
        __syncthreads();
        if (part == 0) {
            a0 += pv1[nn][d2][0];
            a1 += pv1[nn][d2][1];
            bf16 b0 = __float2bfloat16(a0);
            bf16 b1 = __float2bfloat16(a1);
            uint w = (uint)(*(ushort*)&b0) | ((uint)(*(ushort*)&b1) << 16);
            ((uint*)rowv_out)[(size_t)n * (DIM / 2) + d2] = w;
        }
    }
}

// ---------------- Kernel 3: FC + GELU + LN via MFMA ----------------
// block = 256 threads = 4 waves; wave = 16 rows x 128 cols.
__global__ __launch_bounds__(256) void fc_kernel(
    const bf16* __restrict__ rowv,
    const bf16* __restrict__ WfcT,     // [n][k] bf16
    const float* __restrict__ Qbuf,    // residual (d_out)
    const float* __restrict__ bfc,
    const float* __restrict__ gamma,
    const float* __restrict__ beta,
    float* __restrict__ out)
{
    const int lane = threadIdx.x & 63;
    const int wid  = threadIdx.x >> 6;
    const int r0w  = blockIdx.x * 64 + wid * 16;
    if (r0w >= N_NODES) return;

    const int rl = lane & 15;     // A row low / B col low / D col low
    const int kb = lane >> 4;     // k-block: k = kb*8 + j

    f32x4 acc[8];
#pragma unroll
    for (int tcol = 0; tcol < 8; ++tcol) acc[tcol] = (f32x4){0.f, 0.f, 0.f, 0.f};

#pragma unroll
    for (int ks = 0; ks < 4; ++ks) {
        const int k0 = ks * 32;
        bf16x8 afrag = *(const bf16x8*)(rowv + (size_t)(r0w + rl) * DIM + k0 + kb * 8);
#pragma unroll
        for (int tcol = 0; tcol < 8; ++tcol) {
            bf16x8 bfrag = *(const bf16x8*)(WfcT + (size_t)(rl + 16 * tcol) * DIM + k0 + kb * 8);
            acc[tcol] = __builtin_amdgcn_mfma_f32_16x16x32_bf16(afrag, bfrag, acc[tcol], 0, 0, 0);
        }
    }

    // ---- epilogue: + bfc + Q, GELU, LayerNorm over 128 cols ----
    float bfc_r[8], gam_r[8], bet_r[8];
#pragma unroll
    for (int tcol = 0; tcol < 8; ++tcol) {
        bfc_r[tcol] = bfc[rl + 16 * tcol];
        gam_r[tcol] = gamma[rl + 16 * tcol];
        bet_r[tcol] = beta[rl + 16 * tcol];
    }

    float g[8][4];
    float s1[4] = {0.f, 0.f, 0.f, 0.f}, s2[4] = {0.f, 0.f, 0.f, 0.f};
#pragma unroll
    for (int j = 0; j < 4; ++j) {
        const int row = r0w + kb * 4 + j;
        const float* qrow = Qbuf + (size_t)row * DIM;
#pragma unroll
        for (int tcol = 0; tcol < 8; ++tcol) {
            float x = acc[tcol][j] + bfc_r[tcol] + qrow[rl + 16 * tcol];
            float gg = 0.5f * x * (1.0f + erff(x * 0.70710678118654752f));
            g[tcol][j] = gg;
            s1[j] += gg;
            s2[j] += gg * gg;
        }
    }
#pragma unroll
    for (int j = 0; j < 4; ++j) {
#pragma unroll
        for (int off = 1; off < 16; off <<= 1) {
            s1[j] += __shfl_xor(s1[j], off);
            s2[j] += __shfl_xor(s2[j], off);
        }
    }
#pragma unroll
    for (int j = 0; j < 4; ++j) {
        const int row = r0w + kb * 4 + j;
        float mean = s1[j] * (1.0f / DIM);
        float var  = s2[j] * (1.0f / DIM) - mean * mean;
        float invs = rsqrtf(var + LN_EPS);
        float* orow = out + (size_t)row * DIM;
#pragma unroll
        for (int tcol = 0; tcol < 8; ++tcol)
            orow[rl + 16 * tcol] = (g[tcol][j] - mean) * invs * gam_r[tcol] + bet_r[tcol];
    }
}

extern "C" void kernel_launch(void* const* d_in, const int* in_sizes, int n_in,
                              void* d_out, int out_size, void* d_ws, size_t ws_size,
                              hipStream_t stream) {
    (void)in_sizes; (void)n_in; (void)out_size; (void)ws_size;
    const float* h     = (const float*)d_in[0];
    const float* Wq    = (const float*)d_in[1];
    const float* Wk    = (const float*)d_in[2];
    const float* Wv    = (const float*)d_in[3];
    const float* Wfc   = (const float*)d_in[4];
    const float* bfc   = (const float*)d_in[5];
    const float* gamma = (const float*)d_in[6];
    const float* beta  = (const float*)d_in[7];
    const int* nidx    = (const int*)d_in[8];
    const int* nmask   = (const int*)d_in[9];

    bf16* Kbuf  = (bf16*)d_ws;
    bf16* Vbuf  = Kbuf + (size_t)N_NODES * DIM;
    bf16* rowv  = Vbuf + (size_t)N_NODES * DIM;
    bf16* WfcT  = rowv + (size_t)N_NODES * DIM;
    float* Q    = (float*)d_out;

    qkv_kernel<<<N_NODES / ROWS, 128, 0, stream>>>(h, Wq, Wk, Wv, Q, Kbuf, Vbuf);
    prep_kernel<<<DIM, DIM, 0, stream>>>(Wfc, WfcT);
    attn_kernel<<<N_NODES / NPB, 512, 0, stream>>>(Q, Kbuf, Vbuf, nidx, nmask, rowv);
    fc_kernel<<<(N_NODES + 63) / 64, 256, 0, stream>>>(rowv, WfcT, Q, bfc, gamma, beta,
                                                       (float*)d_out);
}

// Round 5
// 118.805 us; speedup vs baseline: 3.0033x; 1.1495x over previous
//
#include <hip/hip_runtime.h>
#include <hip/hip_bf16.h>
#include <math.h>

#define N_NODES 30000
#define MAXN 32
#define DIM 128
#define NHEAD 4
#define HDIM 32
#define NPB 4            // nodes per block in attn kernel
#define LN_EPS 1e-5f

typedef __hip_bfloat16 bf16;
typedef __attribute__((ext_vector_type(8))) short bf16x8;
typedef __attribute__((ext_vector_type(4))) float f32x4;

__device__ inline short bfbits(float f) {
    bf16 b = __float2bfloat16(f);
    return *(short*)&b;
}

// ---------------- prep: W[k][n] f32 -> WT[n][k] bf16 for Wq,Wk,Wv,Wfc ----------------
__global__ __launch_bounds__(128) void prep_kernel(
    const float* __restrict__ Wq, const float* __restrict__ Wk,
    const float* __restrict__ Wv, const float* __restrict__ Wfc,
    bf16* __restrict__ WqT, bf16* __restrict__ WkT,
    bf16* __restrict__ WvT, bf16* __restrict__ WfcT)
{
    const int n = blockIdx.x, k = threadIdx.x;
    WqT[n * DIM + k]  = __float2bfloat16(Wq[k * DIM + n]);
    WkT[n * DIM + k]  = __float2bfloat16(Wk[k * DIM + n]);
    WvT[n * DIM + k]  = __float2bfloat16(Wv[k * DIM + n]);
    WfcT[n * DIM + k] = __float2bfloat16(Wfc[k * DIM + n]);
}

// ---------------- Kernel 1: QKV projection via MFMA ----------------
// 256 threads = 4 waves; wave = 16 rows x 128 cols x {Q,K,V}.
__device__ inline void gemm_pass(const bf16x8 a[4], const bf16* __restrict__ WT,
                                 int rl, int kb, f32x4 acc[8]) {
#pragma unroll
    for (int ks = 0; ks < 4; ++ks) {
        const bf16* wp = WT + (size_t)rl * DIM + ks * 32 + kb * 8;
#pragma unroll
        for (int t = 0; t < 8; ++t) {
            bf16x8 bfrag = *(const bf16x8*)(wp + (size_t)t * 16 * DIM);
            acc[t] = __builtin_amdgcn_mfma_f32_16x16x32_bf16(a[ks], bfrag, acc[t], 0, 0, 0);
        }
    }
}

__global__ __launch_bounds__(256) void qkv_mfma_kernel(
    const float* __restrict__ h,
    const bf16* __restrict__ WqT,
    const bf16* __restrict__ WkT,
    const bf16* __restrict__ WvT,
    float* __restrict__ Qout,
    bf16* __restrict__ Kout,
    bf16* __restrict__ Vout)
{
    const int lane = threadIdx.x & 63;
    const int wid  = threadIdx.x >> 6;
    const int r0w  = blockIdx.x * 64 + wid * 16;
    const int rl = lane & 15;     // A row low / out col low
    const int kb = lane >> 4;     // k-block

    // preload + convert A fragments: row r0w+rl, k = ks*32 + kb*8 + [0..8)
    const int arow = min(r0w + rl, N_NODES - 1);
    const float* hrow = h + (size_t)arow * DIM + kb * 8;
    bf16x8 a[4];
#pragma unroll
    for (int ks = 0; ks < 4; ++ks) {
        float4 f0 = *(const float4*)(hrow + ks * 32);
        float4 f1 = *(const float4*)(hrow + ks * 32 + 4);
        bf16x8 v;
        v[0] = bfbits(f0.x); v[1] = bfbits(f0.y); v[2] = bfbits(f0.z); v[3] = bfbits(f0.w);
        v[4] = bfbits(f1.x); v[5] = bfbits(f1.y); v[6] = bfbits(f1.z); v[7] = bfbits(f1.w);
        a[ks] = v;
    }

    f32x4 acc[8];

    // ---- Q ----
#pragma unroll
    for (int t = 0; t < 8; ++t) acc[t] = (f32x4){0.f, 0.f, 0.f, 0.f};
    gemm_pass(a, WqT, rl, kb, acc);
#pragma unroll
    for (int j = 0; j < 4; ++j) {
        const int row = r0w + kb * 4 + j;
        if (row < N_NODES) {
            float* orow = Qout + (size_t)row * DIM;
#pragma unroll
            for (int t = 0; t < 8; ++t) orow[rl + 16 * t] = acc[t][j];
        }
    }

    // ---- K ----
#pragma unroll
    for (int t = 0; t < 8; ++t) acc[t] = (f32x4){0.f, 0.f, 0.f, 0.f};
    gemm_pass(a, WkT, rl, kb, acc);
#pragma unroll
    for (int j = 0; j < 4; ++j) {
        const int row = r0w + kb * 4 + j;
        if (row < N_NODES) {
            bf16* orow = Kout + (size_t)row * DIM;
#pragma unroll
            for (int t = 0; t < 8; ++t) orow[rl + 16 * t] = __float2bfloat16(acc[t][j]);
        }
    }

    // ---- V ----
#pragma unroll
    for (int t = 0; t < 8; ++t) acc[t] = (f32x4){0.f, 0.f, 0.f, 0.f};
    gemm_pass(a, WvT, rl, kb, acc);
#pragma unroll
    for (int j = 0; j < 4; ++j) {
        const int row = r0w + kb * 4 + j;
        if (row < N_NODES) {
            bf16* orow = Vout + (size_t)row * DIM;
#pragma unroll
            for (int t = 0; t < 8; ++t) orow[rl + 16 * t] = __float2bfloat16(acc[t][j]);
        }
    }
}

__device__ inline float bf_hi(uint w) { return __uint_as_float(w & 0xffff0000u); }
__device__ inline float bf_lo(uint w) { return __uint_as_float((w & 0xffffu) << 16); }

// ---------------- Kernel 2: gather-attention only ----------------
// NPB nodes per 512-thread block; 128 threads per node. Writes rowv (bf16).
__global__ __launch_bounds__(512, 8) void attn_kernel(
    const float* __restrict__ Qbuf,
    const bf16* __restrict__ Kbuf,
    const bf16* __restrict__ Vbuf,
    const int* __restrict__ nidx,
    const int* __restrict__ nmask,
    bf16* __restrict__ rowv_out)
{
    __shared__ float qs[NPB][DIM];
    __shared__ float al[NPB][NHEAD][MAXN];
    __shared__ float pv1[NPB][64][2];
    __shared__ int   idx_s[NPB][MAXN];

    const int t  = threadIdx.x;
    const int nn = t >> 7;
    const int tl = t & 127;
    const int n  = blockIdx.x * NPB + nn;

    qs[nn][tl] = Qbuf[(size_t)n * DIM + tl];
    if (tl < MAXN) idx_s[nn][tl] = nidx[(size_t)n * MAXN + tl];
    __syncthreads();

    // ---- scores + softmax: tl = h*32 + m ----
    {
        const int hh = tl >> 5;
        const int m  = tl & 31;
        const uint4* kp = (const uint4*)((const ushort*)Kbuf
                          + (size_t)idx_s[nn][m] * DIM + hh * HDIM);
        const float4* qp4 = (const float4*)(&qs[nn][hh * HDIM]);
        float acc = 0.f;
#pragma unroll
        for (int c = 0; c < 4; ++c) {
            uint4 kd = kp[c];
            float4 q0 = qp4[2 * c], q1 = qp4[2 * c + 1];
            acc = fmaf(q0.x, bf_lo(kd.x), acc);
            acc = fmaf(q0.y, bf_hi(kd.x), acc);
            acc = fmaf(q0.z, bf_lo(kd.y), acc);
            acc = fmaf(q0.w, bf_hi(kd.y), acc);
            acc = fmaf(q1.x, bf_lo(kd.z), acc);
            acc = fmaf(q1.y, bf_hi(kd.z), acc);
            acc = fmaf(q1.z, bf_lo(kd.w), acc);
            acc = fmaf(q1.w, bf_hi(kd.w), acc);
        }
        acc *= 0.17677669529663687f;            // 1/sqrt(32)
        if (nmask[(size_t)n * MAXN + m] == 0) acc = -1e9f;

        float mx = acc;
#pragma unroll
        for (int off = 1; off < 32; off <<= 1)
            mx = fmaxf(mx, __shfl_xor(mx, off));
        float e = expf(acc - mx);
        float s = e;
#pragma unroll
        for (int off = 1; off < 32; off <<= 1)
            s += __shfl_xor(s, off);
        al[nn][hh][m] = e / s;
    }
    __syncthreads();

    // ---- weighted V sum: 2-way m-split, packed bf16x2 loads ----
    {
        const int part = tl >> 6;     // 0: m 0..15, 1: m 16..31
        const int d2   = tl & 63;     // dim pair (2*d2, 2*d2+1)
        const int hh2  = d2 >> 4;
        const uint* vb = (const uint*)Vbuf;
        float a0 = 0.f, a1 = 0.f;
#pragma unroll
        for (int mm = 0; mm < 16; ++mm) {
            int m = part * 16 + mm;
            uint v = vb[(size_t)idx_s[nn][m] * (DIM / 2) + d2];
            float alv = al[nn][hh2][m];
            a0 = fmaf(alv, bf_lo(v), a0);
            a1 = fmaf(alv, bf_hi(v), a1);
        }
        if (part == 1) { pv1[nn][d2][0] = a0; pv1[nn][d2][1] = a1; }
        __syncthreads();
        if (part == 0) {
            a0 += pv1[nn][d2][0];
            a1 += pv1[nn][d2][1];
            bf16 b0 = __float2bfloat16(a0);
            bf16 b1 = __float2bfloat16(a1);
            uint w = (uint)(*(ushort*)&b0) | ((uint)(*(ushort*)&b1) << 16);
            ((uint*)rowv_out)[(size_t)n * (DIM / 2) + d2] = w;
        }
    }
}

// ---------------- Kernel 3: FC + GELU + LN via MFMA ----------------
// block = 256 threads = 4 waves; wave = 16 rows x 128 cols.
__global__ __launch_bounds__(256) void fc_kernel(
    const bf16* __restrict__ rowv,
    const bf16* __restrict__ WfcT,     // [n][k] bf16
    const float* __restrict__ Qbuf,    // residual (d_out)
    const float* __restrict__ bfc,
    const float* __restrict__ gamma,
    const float* __restrict__ beta,
    float* __restrict__ out)
{
    const int lane = threadIdx.x & 63;
    const int wid  = threadIdx.x >> 6;
    const int r0w  = blockIdx.x * 64 + wid * 16;
    if (r0w >= N_NODES) return;

    const int rl = lane & 15;
    const int kb = lane >> 4;

    f32x4 acc[8];
#pragma unroll
    for (int tcol = 0; tcol < 8; ++tcol) acc[tcol] = (f32x4){0.f, 0.f, 0.f, 0.f};

#pragma unroll
    for (int ks = 0; ks < 4; ++ks) {
        const int k0 = ks * 32;
        bf16x8 afrag = *(const bf16x8*)(rowv + (size_t)(r0w + rl) * DIM + k0 + kb * 8);
#pragma unroll
        for (int tcol = 0; tcol < 8; ++tcol) {
            bf16x8 bfrag = *(const bf16x8*)(WfcT + (size_t)(rl + 16 * tcol) * DIM + k0 + kb * 8);
            acc[tcol] = __builtin_amdgcn_mfma_f32_16x16x32_bf16(afrag, bfrag, acc[tcol], 0, 0, 0);
        }
    }

    float bfc_r[8], gam_r[8], bet_r[8];
#pragma unroll
    for (int tcol = 0; tcol < 8; ++tcol) {
        bfc_r[tcol] = bfc[rl + 16 * tcol];
        gam_r[tcol] = gamma[rl + 16 * tcol];
        bet_r[tcol] = beta[rl + 16 * tcol];
    }

    float g[8][4];
    float s1[4] = {0.f, 0.f, 0.f, 0.f}, s2[4] = {0.f, 0.f, 0.f, 0.f};
#pragma unroll
    for (int j = 0; j < 4; ++j) {
        const int row = r0w + kb * 4 + j;
        const float* qrow = Qbuf + (size_t)row * DIM;
#pragma unroll
        for (int tcol = 0; tcol < 8; ++tcol) {
            float x = acc[tcol][j] + bfc_r[tcol] + qrow[rl + 16 * tcol];
            float gg = 0.5f * x * (1.0f + erff(x * 0.70710678118654752f));
            g[tcol][j] = gg;
            s1[j] += gg;
            s2[j] += gg * gg;
        }
    }
#pragma unroll
    for (int j = 0; j < 4; ++j) {
#pragma unroll
        for (int off = 1; off < 16; off <<= 1) {
            s1[j] += __shfl_xor(s1[j], off);
            s2[j] += __shfl_xor(s2[j], off);
        }
    }
#pragma unroll
    for (int j = 0; j < 4; ++j) {
        const int row = r0w + kb * 4 + j;
        float mean = s1[j] * (1.0f / DIM);
        float var  = s2[j] * (1.0f / DIM) - mean * mean;
        float invs = rsqrtf(var + LN_EPS);
        float* orow = out + (size_t)row * DIM;
#pragma unroll
        for (int tcol = 0; tcol < 8; ++tcol)
            orow[rl + 16 * tcol] = (g[tcol][j] - mean) * invs * gam_r[tcol] + bet_r[tcol];
    }
}

extern "C" void kernel_launch(void* const* d_in, const int* in_sizes, int n_in,
                              void* d_out, int out_size, void* d_ws, size_t ws_size,
                              hipStream_t stream) {
    (void)in_sizes; (void)n_in; (void)out_size; (void)ws_size;
    const float* h     = (const float*)d_in[0];
    const float* Wq    = (const float*)d_in[1];
    const float* Wk    = (const float*)d_in[2];
    const float* Wv    = (const float*)d_in[3];
    const float* Wfc   = (const float*)d_in[4];
    const float* bfc   = (const float*)d_in[5];
    const float* gamma = (const float*)d_in[6];
    const float* beta  = (const float*)d_in[7];
    const int* nidx    = (const int*)d_in[8];
    const int* nmask   = (const int*)d_in[9];

    bf16* Kbuf  = (bf16*)d_ws;
    bf16* Vbuf  = Kbuf + (size_t)N_NODES * DIM;
    bf16* rowv  = Vbuf + (size_t)N_NODES * DIM;
    bf16* WqT   = rowv + (size_t)N_NODES * DIM;
    bf16* WkT   = WqT + (size_t)DIM * DIM;
    bf16* WvT   = WkT + (size_t)DIM * DIM;
    bf16* WfcT  = WvT + (size_t)DIM * DIM;
    float* Q    = (float*)d_out;

    prep_kernel<<<DIM, DIM, 0, stream>>>(Wq, Wk, Wv, Wfc, WqT, WkT, WvT, WfcT);
    qkv_mfma_kernel<<<(N_NODES + 63) / 64, 256, 0, stream>>>(h, WqT, WkT, WvT, Q, Kbuf, Vbuf);
    attn_kernel<<<N_NODES / NPB, 512, 0, stream>>>(Q, Kbuf, Vbuf, nidx, nmask, rowv);
    fc_kernel<<<(N_NODES + 63) / 64, 256, 0, stream>>>(rowv, WfcT, Q, bfc, gamma, beta,
                                                       (float*)d_out);
}